// Round 18
// baseline (275.659 us; speedup 1.0000x reference)
//
#include <hip/hip_runtime.h>
#include <hip/hip_bf16.h>
#include <math.h>

constexpr int T   = 1024;
constexpr int H   = 2048;
constexpr int I   = 1024;
constexpr int E   = 8;
constexpr int NEZ = 16;   // E + Z
constexpr int TK  = 4;    // TOP_K
constexpr int MTG = 24;   // max m-microtiles per expert (384 rows)

typedef short bf16x8 __attribute__((ext_vector_type(8)));
typedef float f32x4  __attribute__((ext_vector_type(4)));
typedef unsigned short u16;
typedef u16 u16x4 __attribute__((ext_vector_type(4)));
typedef u16 u16x8 __attribute__((ext_vector_type(8)));

// raw barrier: lgkm drain (LDS ops visible) WITHOUT vmcnt(0) drain
#define SYNC() do { asm volatile("s_waitcnt lgkmcnt(0)" ::: "memory"); \
                    __builtin_amdgcn_s_barrier(); } while (0)

__device__ __forceinline__ u16 bf16rn(float x) {
  unsigned u = __builtin_bit_cast(unsigned, x);
  u = u + 0x7FFFu + ((u >> 16) & 1u);
  return (u16)(u >> 16);
}
__device__ __forceinline__ float bf16tof(u16 h) {
  return __builtin_bit_cast(float, (unsigned)h << 16);
}

// ---------------------------------------------------------------------------
// prep_a: gather+convert x rows per expert into microtile planes
// Axh/Axl [e][kt=64][mtg=MTG][64][8].
// ---------------------------------------------------------------------------
__global__ __launch_bounds__(256) void prep_a_kernel(
    const float* __restrict__ x, const int* __restrict__ cnt,
    const int* __restrict__ list, u16* __restrict__ Axh, u16* __restrict__ Axl)
{
  const int kt = blockIdx.x;   // 0..63
  const int e  = blockIdx.y;   // 0..7
  int ce = cnt[e]; if (ce > MTG * 16) ce = MTG * 16;
  if (ce == 0) return;
  const int tid = threadIdx.x;
  const int w = tid >> 6, lane = tid & 63;
  const int l15 = lane & 15, lg = lane >> 4;

  for (int mtg = w; mtg < MTG; mtg += 4) {
    int r = mtg * 16 + l15; if (r >= ce) r = ce - 1;
    const int tok = list[e * T + r] >> 2;
    const float* src = x + (size_t)tok * H + kt * 32 + lg * 8;
    const float4 v0 = *(const float4*)(src);
    const float4 v1 = *(const float4*)(src + 4);
    const float vv[8] = {v0.x, v0.y, v0.z, v0.w, v1.x, v1.y, v1.z, v1.w};
    u16x8 h8, l8;
#pragma unroll
    for (int j = 0; j < 8; j++) {
      const u16 hh = bf16rn(vv[j]);
      h8[j] = hh;
      l8[j] = bf16rn(vv[j] - bf16tof(hh));
    }
    const size_t off = (((size_t)e * 64 + kt) * MTG + mtg) * 512 + (size_t)lane * 8;
    *(u16x8*)(Axh + off) = h8;
    *(u16x8*)(Axl + off) = l8;
  }
}

// ---------------------------------------------------------------------------
// Router (unchanged, fp32-exact selection).
// ---------------------------------------------------------------------------
__global__ __launch_bounds__(256) void router_kernel(
    const float* __restrict__ x, const float* __restrict__ rw,
    const float* __restrict__ bias, int* __restrict__ cnt,
    int* __restrict__ list, float* __restrict__ wk4,
    float* __restrict__ zerow)
{
  const int t   = blockIdx.x;
  const int tid = threadIdx.x;
  const float* xt = x + (size_t)t * H;

  float acc[NEZ];
#pragma unroll
  for (int e = 0; e < NEZ; e++) acc[e] = 0.f;

  for (int h = tid; h < H; h += 256) {
    const float xv = xt[h];
#pragma unroll
    for (int e = 0; e < NEZ; e++) acc[e] = fmaf(xv, rw[e * H + h], acc[e]);
  }

#pragma unroll
  for (int e = 0; e < NEZ; e++) {
    float v = acc[e];
#pragma unroll
    for (int off = 32; off >= 1; off >>= 1) v += __shfl_down(v, off, 64);
    acc[e] = v;
  }

  __shared__ float red[4][NEZ];
  const int wv = tid >> 6, ln = tid & 63;
  if (ln == 0) {
#pragma unroll
    for (int e = 0; e < NEZ; e++) red[wv][e] = acc[e];
  }
  __syncthreads();

  if (tid == 0) {
    float l[NEZ];
    float mx = -1e30f;
#pragma unroll
    for (int e = 0; e < NEZ; e++) {
      l[e] = red[0][e] + red[1][e] + red[2][e] + red[3][e];
      mx = fmaxf(mx, l[e]);
    }
    float s = 0.f;
#pragma unroll
    for (int e = 0; e < NEZ; e++) { l[e] = expf(l[e] - mx); s += l[e]; }
    const float inv = 1.f / s;
    float sc[NEZ], sel[NEZ];
#pragma unroll
    for (int e = 0; e < NEZ; e++) {
      sc[e]  = l[e] * inv;
      sel[e] = sc[e] + bias[e];
    }
    float zw = 0.f;
#pragma unroll
    for (int k = 0; k < TK; k++) {
      int best = 0; float bv = sel[0];
#pragma unroll
      for (int e = 1; e < NEZ; e++) {
        if (sel[e] > bv) { bv = sel[e]; best = e; }
      }
      sel[best] = -1e30f;
      const float w = sc[best];
      if (best < E) {
        const int pos = atomicAdd(&cnt[best], 1);
        list[best * T + pos] = (t << 2) | k;
        wk4[t * TK + k] = w;
      } else {
        wk4[t * TK + k] = 0.f;
        zw += w;
      }
    }
    zerow[t] = zw;
  }
}

// ---------------------------------------------------------------------------
// Gate+Up grouped GEMM — r14 structure with BN=16 (2 blocks/CU). 256 thr /
// 4 waves; wave = one 64m tier, BN=16, BK=32, 64 bodies. Per body per
// thread: 4 strided fp32 (mat,kq,nl duty), converted once into 3 x 4KB LDS
// rotation; A direct global->VGPR. NO B duplication (tg=1 dead at ntiers<=4).
// Grid 1024 = 8e x (64nu x 2tg) -> 512 live = 2 blocks/CU, 2 waves/SIMD.
// ---------------------------------------------------------------------------
__global__ __launch_bounds__(256, 2) void gateup_kernel(
    const u16* __restrict__ Axh, const u16* __restrict__ Axl,
    const float* __restrict__ wg, const float* __restrict__ wu,
    const int* __restrict__ cnt, const int* __restrict__ list,
    u16* __restrict__ midh, u16* __restrict__ midl)
{
  const int p = blockIdx.x;
  const int L = (p & 7) * 128 + (p >> 3);   // XCD == expert
  const int e = L >> 7;
  const int rem = L & 127;
  const int nu = rem >> 1;
  const int tg = rem & 1;
  const int n0 = nu * 16;
  int ce = cnt[e]; if (ce > MTG * 16) ce = MTG * 16;
  if (ce == 0) return;
  const int ntiers = (ce + 63) >> 6;
  if (tg == 1 && ntiers <= 4) return;       // tail blocks usually dead

  __shared__ __align__(16) char ldsB[3][4096];

  const int tid = threadIdx.x;
  const int w = tid >> 6, lane = tid & 63;
  const int l15 = lane & 15, lg = lane >> 4;
  const int tier = tg * 4 + w;
  const bool alive = (tier < ntiers);

  // conversion duty: thread -> (mat, kq, nl); 4 k each
  const int mat = tid >> 7;            // 0 = gate, 1 = up
  const int kq  = (tid >> 4) & 7;      // k-quad (4 k)
  const int nl  = tid & 15;            // local n (BN=16)
  const int Lw  = nl | ((kq >> 1) << 4);
  const int foh = mat * 2048 + Lw * 16 + (kq & 1) * 8;   // hi; lo at +1024
  const float* wsrc = (mat ? wu : wg) + (size_t)e * H * I +
                      (size_t)(kq * 4) * I + (size_t)(n0 + nl);

  // A pointers (clamped for dead tiers)
  const int mt0 = (tier <= 5) ? tier * 4 : MTG - 4;
  const char* pAh = (const char*)Axh + (((size_t)e * 64) * MTG + mt0) * 1024 + (size_t)lane * 16;
  const char* pAl = (const char*)Axl + (((size_t)e * 64) * MTG + mt0) * 1024 + (size_t)lane * 16;

  f32x4 accg[4] = {};
  f32x4 accu[4] = {};
  bf16x8 a0[8], a1[8], a2[8];
  float s0[4], s1[4], s2[4];

  constexpr int NB = 64;

#define GU_ISSUE(S, KT) do {                                              \
    const float* ps_ = wsrc + (size_t)(KT) * (32 * (size_t)I);            \
    _Pragma("unroll") for (int j = 0; j < 4; j++) S[j] = ps_[(size_t)j * I]; \
  } while (0)

#define GU_ALOAD(A, KT) do {                                              \
    const size_t ka_ = (size_t)(KT) * (MTG * 1024);                       \
    _Pragma("unroll") for (int qn = 0; qn < 4; qn++) {                    \
      A[qn]     = *(const bf16x8*)(pAh + ka_ + qn * 1024);                \
      A[4 + qn] = *(const bf16x8*)(pAl + ka_ + qn * 1024);                \
    } } while (0)

#define GU_CONVW(S, WB) do {                                              \
    u16x4 h4_, l4_;                                                       \
    _Pragma("unroll") for (int j = 0; j < 4; j++) {                       \
      const u16 hh_ = bf16rn(S[j]);                                       \
      h4_[j] = hh_; l4_[j] = bf16rn(S[j] - bf16tof(hh_)); }               \
    *(u16x4*)(&ldsB[WB][0] + foh)        = h4_;                           \
    *(u16x4*)(&ldsB[WB][0] + foh + 1024) = l4_;                           \
  } while (0)

#define GU_COMP(RB, A) do {                                               \
    const char* bp_ = &ldsB[RB][0];                                       \
    const bf16x8 ggh = *(const bf16x8*)(bp_        + lane * 16);          \
    const bf16x8 ggl = *(const bf16x8*)(bp_ + 1024 + lane * 16);          \
    const bf16x8 guh = *(const bf16x8*)(bp_ + 2048 + lane * 16);          \
    const bf16x8 gul = *(const bf16x8*)(bp_ + 3072 + lane * 16);          \
    _Pragma("unroll") for (int mi = 0; mi < 4; mi++) {                    \
      accg[mi] = __builtin_amdgcn_mfma_f32_16x16x32_bf16(A[mi],     ggh, accg[mi], 0, 0, 0); \
      accg[mi] = __builtin_amdgcn_mfma_f32_16x16x32_bf16(A[mi],     ggl, accg[mi], 0, 0, 0); \
      accg[mi] = __builtin_amdgcn_mfma_f32_16x16x32_bf16(A[4 + mi], ggh, accg[mi], 0, 0, 0); \
      accu[mi] = __builtin_amdgcn_mfma_f32_16x16x32_bf16(A[mi],     guh, accu[mi], 0, 0, 0); \
      accu[mi] = __builtin_amdgcn_mfma_f32_16x16x32_bf16(A[mi],     gul, accu[mi], 0, 0, 0); \
      accu[mi] = __builtin_amdgcn_mfma_f32_16x16x32_bf16(A[4 + mi], guh, accu[mi], 0, 0, 0); \
    } } while (0)

#define GU_BODY(K, SI, AU, AN, SC, RB, WB) do {                           \
    const int k_ = (K);                                                   \
    SYNC();                                                               \
    if (k_ + 3 < NB) GU_ISSUE(SI, k_ + 3);                                \
    if (k_ + 1 < NB) GU_ALOAD(AN, k_ + 1);                                \
    if (alive) GU_COMP(RB, AU);                                           \
    if (k_ + 1 < NB) GU_CONVW(SC, WB);                                    \
  } while (0)

  GU_ISSUE(s0, 0); GU_ISSUE(s1, 1); GU_ISSUE(s2, 2);
  GU_ALOAD(a0, 0);
  GU_CONVW(s0, 0);

  for (int kb = 0; kb < 63; kb += 3) {
    GU_BODY(kb,     s0, a0, a1, s1, 0, 1);
    GU_BODY(kb + 1, s1, a1, a2, s2, 1, 2);
    GU_BODY(kb + 2, s2, a2, a0, s0, 2, 0);
  }
  GU_BODY(63, s0, a0, a1, s1, 0, 1);

#undef GU_ISSUE
#undef GU_ALOAD
#undef GU_CONVW
#undef GU_COMP
#undef GU_BODY

  // epilogue: silu(g)*u -> bf16 hi/lo mid in microtile layout [e][ktI][MTG][512]
  if (alive) {
#pragma unroll
    for (int mi = 0; mi < 4; mi++) {
#pragma unroll
      for (int rr = 0; rr < 4; rr++) {
        const int m = tier * 64 + mi * 16 + lg * 4 + rr;
        if (m >= ce) continue;
        const int n = n0 + l15;
        const float g = accg[mi][rr];
        const float u = accu[mi][rr];
        const float mv = (g / (1.f + expf(-g))) * u;
        const u16 hh = bf16rn(mv);
        const size_t off =
            (((size_t)e * 32 + (n >> 5)) * MTG + (m >> 4)) * 512 +
            (size_t)((m & 15) + ((n >> 3) & 3) * 16) * 8 + (n & 7);
        midh[off] = hh;
        midl[off] = bf16rn(mv - bf16tof(hh));
      }
    }
  }
}

// ---------------------------------------------------------------------------
// Down grouped GEMM — r14 structure with BN=32 (2 blocks/CU). 256 thr /
// 4 waves; BM=256, BN=32, 32 bodies BK=32. Per body per thread: 4 strided
// fp32 wd dwords converted once into 3 x 4KB LDS. A = microtiled mid.
// Grid 1024 = 8e x (64nu x 2tg) -> 512 live = 2 blocks/CU.
// ---------------------------------------------------------------------------
__global__ __launch_bounds__(256, 2) void down_kernel(
    const u16* __restrict__ midh, const u16* __restrict__ midl,
    const float* __restrict__ wd,
    const int* __restrict__ cnt, const int* __restrict__ list,
    float* __restrict__ downb)
{
  const int p = blockIdx.x;
  const int L = (p & 7) * 128 + (p >> 3);
  const int e = L >> 7;
  const int rem = L & 127;
  const int nu = rem >> 1;
  const int tg = rem & 1;
  const int n0 = nu * 32;
  int ce = cnt[e]; if (ce > MTG * 16) ce = MTG * 16;
  if (ce == 0) return;
  const int ntiers = (ce + 63) >> 6;
  if (tg == 1 && ntiers <= 4) return;

  __shared__ __align__(16) char ldsB[3][4096];

  const int tid = threadIdx.x;
  const int w = tid >> 6, lane = tid & 63;
  const int l15 = lane & 15, lg = lane >> 4;
  const int tier = tg * 4 + w;
  const bool alive = (tier < ntiers);

  // conversion duty: thread -> (kq, nl); 4 k each
  const int kq = tid >> 5;             // 0..7 (k-quad)
  const int nl = tid & 31;
  const int ntgw = nl >> 4;
  const int Lw  = (nl & 15) | ((kq >> 1) << 4);
  const int foh = ntgw * 1024 + Lw * 16 + (kq & 1) * 8;   // hi; lo at +2048
  const float* wsrc = wd + (size_t)e * I * H + (size_t)(kq * 4) * H + (size_t)(n0 + nl);

  const int mt0 = (tier <= 5) ? tier * 4 : MTG - 4;
  const char* pAh = (const char*)midh + (((size_t)e * 32) * MTG + mt0) * 1024 + (size_t)lane * 16;
  const char* pAl = (const char*)midl + (((size_t)e * 32) * MTG + mt0) * 1024 + (size_t)lane * 16;

  f32x4 acc[4][2] = {};
  bf16x8 a0[8], a1[8], a2[8];
  float s0[4], s1[4], s2[4];

  constexpr int NB = 32;

#define DN_ISSUE(S, KT) do {                                              \
    const float* ps_ = wsrc + (size_t)(KT) * (32 * (size_t)H);            \
    _Pragma("unroll") for (int j = 0; j < 4; j++) S[j] = ps_[(size_t)j * H]; \
  } while (0)

#define DN_ALOAD(A, KT) do {                                              \
    const size_t ka_ = (size_t)(KT) * (MTG * 1024);                       \
    _Pragma("unroll") for (int qn = 0; qn < 4; qn++) {                    \
      A[qn]     = *(const bf16x8*)(pAh + ka_ + qn * 1024);                \
      A[4 + qn] = *(const bf16x8*)(pAl + ka_ + qn * 1024);                \
    } } while (0)

#define DN_CONVW(S, WB) do {                                              \
    u16x4 h4_, l4_;                                                       \
    _Pragma("unroll") for (int j = 0; j < 4; j++) {                       \
      const u16 hh_ = bf16rn(S[j]);                                       \
      h4_[j] = hh_; l4_[j] = bf16rn(S[j] - bf16tof(hh_)); }               \
    *(u16x4*)(&ldsB[WB][0] + foh)        = h4_;                           \
    *(u16x4*)(&ldsB[WB][0] + foh + 2048) = l4_;                           \
  } while (0)

#define DN_COMP(RB, A) do {                                               \
    const char* bp_ = &ldsB[RB][0];                                       \
    _Pragma("unroll") for (int ntg = 0; ntg < 2; ntg++) {                 \
      const bf16x8 bh = *(const bf16x8*)(bp_ + ntg * 1024        + lane * 16); \
      const bf16x8 bl = *(const bf16x8*)(bp_ + ntg * 1024 + 2048 + lane * 16); \
      _Pragma("unroll") for (int mi = 0; mi < 4; mi++) {                  \
        acc[mi][ntg] = __builtin_amdgcn_mfma_f32_16x16x32_bf16(A[mi],     bh, acc[mi][ntg], 0, 0, 0); \
        acc[mi][ntg] = __builtin_amdgcn_mfma_f32_16x16x32_bf16(A[mi],     bl, acc[mi][ntg], 0, 0, 0); \
        acc[mi][ntg] = __builtin_amdgcn_mfma_f32_16x16x32_bf16(A[4 + mi], bh, acc[mi][ntg], 0, 0, 0); \
      } } } while (0)

#define DN_BODY(K, SI, AU, AN, SC, RB, WB) do {                           \
    const int k_ = (K);                                                   \
    SYNC();                                                               \
    if (k_ + 3 < NB) DN_ISSUE(SI, k_ + 3);                                \
    if (k_ + 1 < NB) DN_ALOAD(AN, k_ + 1);                                \
    if (alive) DN_COMP(RB, AU);                                           \
    if (k_ + 1 < NB) DN_CONVW(SC, WB);                                    \
  } while (0)

  DN_ISSUE(s0, 0); DN_ISSUE(s1, 1); DN_ISSUE(s2, 2);
  DN_ALOAD(a0, 0);
  DN_CONVW(s0, 0);

  for (int kb = 0; kb < 30; kb += 3) {
    DN_BODY(kb,     s0, a0, a1, s1, 0, 1);
    DN_BODY(kb + 1, s1, a1, a2, s2, 1, 2);
    DN_BODY(kb + 2, s2, a2, a0, s0, 2, 0);
  }
  DN_BODY(30, s0, a0, a1, s1, 0, 1);
  DN_BODY(31, s1, a1, a2, s2, 1, 2);

#undef DN_ISSUE
#undef DN_ALOAD
#undef DN_CONVW
#undef DN_COMP
#undef DN_BODY

  if (alive) {
#pragma unroll
    for (int mi = 0; mi < 4; mi++) {
#pragma unroll
      for (int rr = 0; rr < 4; rr++) {
        const int m = tier * 64 + mi * 16 + lg * 4 + rr;
        if (m >= ce) continue;
        const int ent  = list[e * T + m];
        const int tok  = ent >> 2;
        const int slot = ent & 3;
        float* drow = downb + ((size_t)tok * TK + slot) * H;
#pragma unroll
        for (int ntg = 0; ntg < 2; ntg++) {
          const int n = n0 + ntg * 16 + l15;
          drow[n] = acc[mi][ntg][rr];
        }
      }
    }
  }
}

// ---------------------------------------------------------------------------
// Combine (unchanged).
// ---------------------------------------------------------------------------
__global__ __launch_bounds__(256) void combine_kernel(
    const float* __restrict__ x, const float* __restrict__ downb,
    const float* __restrict__ wk4, const float* __restrict__ zerow,
    float* __restrict__ out)
{
  const int idx = blockIdx.x * 256 + threadIdx.x;
  const int t   = idx >> 9;
  const int h   = (idx & 511) * 4;

  const float w0 = wk4[t * TK + 0];
  const float w1 = wk4[t * TK + 1];
  const float w2 = wk4[t * TK + 2];
  const float w3 = wk4[t * TK + 3];
  const float zw = zerow[t];

  const float4 xv = *(const float4*)(x + (size_t)t * H + h);
  const float4 d0 = *(const float4*)(downb + ((size_t)t * TK + 0) * H + h);
  const float4 d1 = *(const float4*)(downb + ((size_t)t * TK + 1) * H + h);
  const float4 d2 = *(const float4*)(downb + ((size_t)t * TK + 2) * H + h);
  const float4 d3 = *(const float4*)(downb + ((size_t)t * TK + 3) * H + h);

  float4 o;
  o.x = w0 * d0.x + w1 * d1.x + w2 * d2.x + w3 * d3.x + zw * xv.x;
  o.y = w0 * d0.y + w1 * d1.y + w2 * d2.y + w3 * d3.y + zw * xv.y;
  o.z = w0 * d0.z + w1 * d1.z + w2 * d2.z + w3 * d3.z + zw * xv.z;
  o.w = w0 * d0.w + w1 * d1.w + w2 * d2.w + w3 * d3.w + zw * xv.w;
  *(float4*)(out + (size_t)t * H + h) = o;
}

// ---------------------------------------------------------------------------
// Workspace (~70 MiB): cnt/list/wk4/zerow + Axh/Axl 12.6 MiB ea +
// midh/midl 6.3 MiB ea + downb 32 MiB.
// ---------------------------------------------------------------------------
extern "C" void kernel_launch(void* const* d_in, const int* in_sizes, int n_in,
                              void* d_out, int out_size, void* d_ws, size_t ws_size,
                              hipStream_t stream) {
  const float* x    = (const float*)d_in[0];
  const float* rw   = (const float*)d_in[1];
  const float* bias = (const float*)d_in[2];
  const float* wg   = (const float*)d_in[3];
  const float* wu   = (const float*)d_in[4];
  const float* wd   = (const float*)d_in[5];
  float* out = (float*)d_out;

  char* ws = (char*)d_ws;
  size_t off = 0;
  auto alloc = [&](size_t bytes) {
    void* p = ws + off;
    off = (off + bytes + 1023) & ~(size_t)1023;
    return p;
  };
  int*   cnt   = (int*)  alloc(E * sizeof(int));
  int*   list  = (int*)  alloc((size_t)E * T * sizeof(int));
  float* wk4   = (float*)alloc((size_t)T * TK * sizeof(float));
  float* zerow = (float*)alloc((size_t)T * sizeof(float));
  const size_t AXSZ = (size_t)E * 64 * MTG * 512;          // elems
  u16*   Axh   = (u16*)  alloc(AXSZ * sizeof(u16));
  u16*   Axl   = (u16*)  alloc(AXSZ * sizeof(u16));
  const size_t MIDSZ = (size_t)E * 32 * MTG * 512;         // elems
  u16*   midh  = (u16*)  alloc(MIDSZ * sizeof(u16));
  u16*   midl  = (u16*)  alloc(MIDSZ * sizeof(u16));
  float* downb = (float*)alloc((size_t)T * TK * H * sizeof(float));
  (void)ws_size;

  hipMemsetAsync(cnt, 0, E * sizeof(int), stream);

  router_kernel<<<T, 256, 0, stream>>>(x, rw, bias, cnt, list, wk4, zerow);
  prep_a_kernel<<<dim3(64, 8), 256, 0, stream>>>(x, cnt, list, Axh, Axl);

  gateup_kernel<<<1024, 256, 0, stream>>>(
      Axh, Axl, wg, wu, cnt, list, midh, midl);

  down_kernel<<<1024, 256, 0, stream>>>(
      midh, midl, wd, cnt, list, downb);

  combine_kernel<<<(T * H / 4) / 256, 256, 0, stream>>>(
      x, downb, wk4, zerow, out);
}

// Round 19
// 198.120 us; speedup vs baseline: 1.3914x; 1.3914x over previous
//
#include <hip/hip_runtime.h>
#include <hip/hip_bf16.h>
#include <math.h>

constexpr int T   = 1024;
constexpr int H   = 2048;
constexpr int I   = 1024;
constexpr int E   = 8;
constexpr int NEZ = 16;   // E + Z
constexpr int TK  = 4;    // TOP_K
constexpr int MTG = 24;   // max m-microtiles per expert (384 rows)

typedef short bf16x8 __attribute__((ext_vector_type(8)));
typedef float f32x4  __attribute__((ext_vector_type(4)));
typedef unsigned short u16;
typedef u16 u16x8 __attribute__((ext_vector_type(8)));

// raw barrier: lgkm drain (LDS ops visible) WITHOUT vmcnt(0) drain --
// keeps the deep global-load pipeline alive across bodies.
#define SYNC() do { asm volatile("s_waitcnt lgkmcnt(0)" ::: "memory"); \
                    __builtin_amdgcn_s_barrier(); } while (0)

__device__ __forceinline__ u16 bf16rn(float x) {
  unsigned u = __builtin_bit_cast(unsigned, x);
  u = u + 0x7FFFu + ((u >> 16) & 1u);
  return (u16)(u >> 16);
}
__device__ __forceinline__ float bf16tof(u16 h) {
  return __builtin_bit_cast(float, (unsigned)h << 16);
}

// ---------------------------------------------------------------------------
// prep_a: gather+convert x rows per expert into microtile planes
// Axh/Axl [e][kt=64][mtg=MTG][64][8].
// ---------------------------------------------------------------------------
__global__ __launch_bounds__(256) void prep_a_kernel(
    const float* __restrict__ x, const int* __restrict__ cnt,
    const int* __restrict__ list, u16* __restrict__ Axh, u16* __restrict__ Axl)
{
  const int kt = blockIdx.x;   // 0..63
  const int e  = blockIdx.y;   // 0..7
  int ce = cnt[e]; if (ce > MTG * 16) ce = MTG * 16;
  if (ce == 0) return;
  const int tid = threadIdx.x;
  const int w = tid >> 6, lane = tid & 63;
  const int l15 = lane & 15, lg = lane >> 4;

  for (int mtg = w; mtg < MTG; mtg += 4) {
    int r = mtg * 16 + l15; if (r >= ce) r = ce - 1;
    const int tok = list[e * T + r] >> 2;
    const float* src = x + (size_t)tok * H + kt * 32 + lg * 8;
    const float4 v0 = *(const float4*)(src);
    const float4 v1 = *(const float4*)(src + 4);
    const float vv[8] = {v0.x, v0.y, v0.z, v0.w, v1.x, v1.y, v1.z, v1.w};
    u16x8 h8, l8;
#pragma unroll
    for (int j = 0; j < 8; j++) {
      const u16 hh = bf16rn(vv[j]);
      h8[j] = hh;
      l8[j] = bf16rn(vv[j] - bf16tof(hh));
    }
    const size_t off = (((size_t)e * 64 + kt) * MTG + mtg) * 512 + (size_t)lane * 8;
    *(u16x8*)(Axh + off) = h8;
    *(u16x8*)(Axl + off) = l8;
  }
}

// ---------------------------------------------------------------------------
// Router (unchanged, fp32-exact selection).
// ---------------------------------------------------------------------------
__global__ __launch_bounds__(256) void router_kernel(
    const float* __restrict__ x, const float* __restrict__ rw,
    const float* __restrict__ bias, int* __restrict__ cnt,
    int* __restrict__ list, float* __restrict__ wk4,
    float* __restrict__ zerow)
{
  const int t   = blockIdx.x;
  const int tid = threadIdx.x;
  const float* xt = x + (size_t)t * H;

  float acc[NEZ];
#pragma unroll
  for (int e = 0; e < NEZ; e++) acc[e] = 0.f;

  for (int h = tid; h < H; h += 256) {
    const float xv = xt[h];
#pragma unroll
    for (int e = 0; e < NEZ; e++) acc[e] = fmaf(xv, rw[e * H + h], acc[e]);
  }

#pragma unroll
  for (int e = 0; e < NEZ; e++) {
    float v = acc[e];
#pragma unroll
    for (int off = 32; off >= 1; off >>= 1) v += __shfl_down(v, off, 64);
    acc[e] = v;
  }

  __shared__ float red[4][NEZ];
  const int wv = tid >> 6, ln = tid & 63;
  if (ln == 0) {
#pragma unroll
    for (int e = 0; e < NEZ; e++) red[wv][e] = acc[e];
  }
  __syncthreads();

  if (tid == 0) {
    float l[NEZ];
    float mx = -1e30f;
#pragma unroll
    for (int e = 0; e < NEZ; e++) {
      l[e] = red[0][e] + red[1][e] + red[2][e] + red[3][e];
      mx = fmaxf(mx, l[e]);
    }
    float s = 0.f;
#pragma unroll
    for (int e = 0; e < NEZ; e++) { l[e] = expf(l[e] - mx); s += l[e]; }
    const float inv = 1.f / s;
    float sc[NEZ], sel[NEZ];
#pragma unroll
    for (int e = 0; e < NEZ; e++) {
      sc[e]  = l[e] * inv;
      sel[e] = sc[e] + bias[e];
    }
    float zw = 0.f;
#pragma unroll
    for (int k = 0; k < TK; k++) {
      int best = 0; float bv = sel[0];
#pragma unroll
      for (int e = 1; e < NEZ; e++) {
        if (sel[e] > bv) { bv = sel[e]; best = e; }
      }
      sel[best] = -1e30f;
      const float w = sc[best];
      if (best < E) {
        const int pos = atomicAdd(&cnt[best], 1);
        list[best * T + pos] = (t << 2) | k;
        wk4[t * TK + k] = w;
      } else {
        wk4[t * TK + k] = 0.f;
        zw += w;
      }
    }
    zerow[t] = zw;
  }
}

// ---------------------------------------------------------------------------
// Gate+Up grouped GEMM — FUSED fp32->bf16 conversion (no prep pass).
// 256 thr / 4 waves; BM=256 (wave=64m tier), BN=32, BK=32, 64 bodies.
// Per body: each thread loads one 8-deep fp32 k-column of wg/wu (8 coalesced
// dwords, 3 slots = 2-body lookahead), converts hi/lo ONCE, shares via
// 3 x 8KB LDS microtile bufs. A direct global->VGPR from Ax (L2 slab).
// Raw-barrier sync (no vmcnt drain). 48 MFMA / wave / body.
// Grid 512 = 8e x 32nu x 2tg (tg1 exits unless ntiers>4); XCD == expert.
// ---------------------------------------------------------------------------
__global__ __launch_bounds__(256) void gateup_kernel(
    const u16* __restrict__ Axh, const u16* __restrict__ Axl,
    const float* __restrict__ wg, const float* __restrict__ wu,
    const int* __restrict__ cnt, const int* __restrict__ list,
    u16* __restrict__ midh, u16* __restrict__ midl)
{
  const int p = blockIdx.x;
  const int L = (p & 7) * 64 + (p >> 3);   // XCD chunk == expert
  const int e = L >> 6;
  const int rem = L & 63;
  const int nu = rem & 31;
  const int tg = rem >> 5;
  const int n0 = nu * 32;
  int ce = cnt[e]; if (ce > MTG * 16) ce = MTG * 16;
  if (ce == 0) return;
  const int ntiers = (ce + 63) >> 6;
  if (tg == 1 && ntiers <= 4) return;

  __shared__ __align__(16) char ldsB[3][8192];

  const int tid = threadIdx.x;
  const int w = tid >> 6, lane = tid & 63;
  const int l15 = lane & 15, lg = lane >> 4;
  const int tier = tg * 4 + w;
  const bool alive = (tier < ntiers);

  // conversion duty: thread -> (mat, oct, nl) column of 8 k
  const int mat = tid >> 7;            // 0 = gate, 1 = up
  const int oct = (tid >> 5) & 3;      // k-octet
  const int nl  = tid & 31;            // local n
  const int ntgw = nl >> 4;
  const int Lw   = (nl & 15) | (oct << 4);
  const int foh  = ((mat << 2) | ntgw) * 1024 + Lw * 16;   // hi frag offset
  const float* wsrc = (mat ? wu : wg) + (size_t)e * H * I +
                      (size_t)(oct * 8) * I + (size_t)(n0 + nl);

  // A pointers (clamped for dead tiers)
  const int mt0 = (tier <= 5) ? tier * 4 : MTG - 4;
  const char* pAh = (const char*)Axh + (((size_t)e * 64) * MTG + mt0) * 1024 + (size_t)lane * 16;
  const char* pAl = (const char*)Axl + (((size_t)e * 64) * MTG + mt0) * 1024 + (size_t)lane * 16;

  f32x4 accg[4][2] = {};
  f32x4 accu[4][2] = {};
  bf16x8 a0[8], a1[8], a2[8];
  float s0[8], s1[8], s2[8];

#define GU_ISSUE(S, KT) do {                                              \
    const float* ps_ = wsrc + (size_t)(KT) * (32 * (size_t)I);            \
    _Pragma("unroll") for (int j = 0; j < 8; j++) S[j] = ps_[(size_t)j * I]; \
  } while (0)

#define GU_ALOAD(A, KT) do {                                              \
    const size_t ka_ = (size_t)(KT) * (MTG * 1024);                       \
    _Pragma("unroll") for (int q = 0; q < 4; q++) {                       \
      A[q]     = *(const bf16x8*)(pAh + ka_ + q * 1024);                  \
      A[4 + q] = *(const bf16x8*)(pAl + ka_ + q * 1024);                  \
    } } while (0)

#define GU_CONVW(S, WB) do {                                              \
    u16x8 h8_, l8_;                                                       \
    _Pragma("unroll") for (int j = 0; j < 8; j++) {                       \
      const u16 hh_ = bf16rn(S[j]);                                       \
      h8_[j] = hh_; l8_[j] = bf16rn(S[j] - bf16tof(hh_)); }               \
    *(u16x8*)(&ldsB[WB][0] + foh) = h8_;                                  \
    *(u16x8*)(&ldsB[WB][0] + foh + 2048) = l8_;                           \
  } while (0)

#define GU_COMP(RB, A) do {                                               \
    const char* bp_ = &ldsB[RB][0];                                       \
    _Pragma("unroll") for (int ntg = 0; ntg < 2; ntg++) {                 \
      const bf16x8 ggh = *(const bf16x8*)(bp_ + ntg * 1024        + lane * 16); \
      const bf16x8 ggl = *(const bf16x8*)(bp_ + ntg * 1024 + 2048 + lane * 16); \
      const bf16x8 guh = *(const bf16x8*)(bp_ + ntg * 1024 + 4096 + lane * 16); \
      const bf16x8 gul = *(const bf16x8*)(bp_ + ntg * 1024 + 6144 + lane * 16); \
      _Pragma("unroll") for (int mi = 0; mi < 4; mi++) {                  \
        accg[mi][ntg] = __builtin_amdgcn_mfma_f32_16x16x32_bf16(A[mi],     ggh, accg[mi][ntg], 0, 0, 0); \
        accg[mi][ntg] = __builtin_amdgcn_mfma_f32_16x16x32_bf16(A[mi],     ggl, accg[mi][ntg], 0, 0, 0); \
        accg[mi][ntg] = __builtin_amdgcn_mfma_f32_16x16x32_bf16(A[4 + mi], ggh, accg[mi][ntg], 0, 0, 0); \
        accu[mi][ntg] = __builtin_amdgcn_mfma_f32_16x16x32_bf16(A[mi],     guh, accu[mi][ntg], 0, 0, 0); \
        accu[mi][ntg] = __builtin_amdgcn_mfma_f32_16x16x32_bf16(A[mi],     gul, accu[mi][ntg], 0, 0, 0); \
        accu[mi][ntg] = __builtin_amdgcn_mfma_f32_16x16x32_bf16(A[4 + mi], guh, accu[mi][ntg], 0, 0, 0); \
      } } } while (0)

#define GU_BODY(K, SI, AU, AN, SC, RB, WB) do {                           \
    const int k_ = (K);                                                   \
    SYNC();                                                               \
    if (k_ + 3 < 64) GU_ISSUE(SI, k_ + 3);                                \
    if (k_ + 1 < 64) GU_ALOAD(AN, k_ + 1);                                \
    if (alive) GU_COMP(RB, AU);                                           \
    if (k_ + 1 < 64) GU_CONVW(SC, WB);                                    \
  } while (0)

  GU_ISSUE(s0, 0); GU_ISSUE(s1, 1); GU_ISSUE(s2, 2);
  GU_ALOAD(a0, 0);
  GU_CONVW(s0, 0);

  for (int kb = 0; kb < 63; kb += 3) {
    GU_BODY(kb,     s0, a0, a1, s1, 0, 1);
    GU_BODY(kb + 1, s1, a1, a2, s2, 1, 2);
    GU_BODY(kb + 2, s2, a2, a0, s0, 2, 0);
  }
  GU_BODY(63, s0, a0, a1, s1, 0, 1);

#undef GU_ISSUE
#undef GU_ALOAD
#undef GU_CONVW
#undef GU_COMP
#undef GU_BODY

  // epilogue: silu(g)*u -> bf16 hi/lo mid in microtile layout [e][ktI][MTG][512]
#pragma unroll
  for (int mi = 0; mi < 4; mi++) {
#pragma unroll
    for (int rr = 0; rr < 4; rr++) {
      const int m = tier * 64 + mi * 16 + lg * 4 + rr;
      if (m >= ce) continue;
#pragma unroll
      for (int ntg = 0; ntg < 2; ntg++) {
        const int n = n0 + ntg * 16 + l15;
        const float g = accg[mi][ntg][rr];
        const float u = accu[mi][ntg][rr];
        const float mv = (g / (1.f + expf(-g))) * u;
        const u16 hh = bf16rn(mv);
        const size_t off =
            (((size_t)e * 32 + (n >> 5)) * MTG + (m >> 4)) * 512 +
            (size_t)((m & 15) + ((n >> 3) & 3) * 16) * 8 + (n & 7);
        midh[off] = hh;
        midl[off] = bf16rn(mv - bf16tof(hh));
      }
    }
  }
}

// ---------------------------------------------------------------------------
// Down grouped GEMM — FUSED conversion of wd. 256 thr / 4 waves; BM=256,
// BN=64, K=I (32 bodies). Thread loads one 8-deep fp32 k-column of wd
// (64-lane-contiguous dwords), converts once, shares via 3 x 8KB LDS.
// A = microtiled mid, direct ping-pong. 48 MFMA / wave / body.
// Grid 512 = 8e x 32nu x 2tg. Scatter epilogue via token list.
// ---------------------------------------------------------------------------
__global__ __launch_bounds__(256) void down_kernel(
    const u16* __restrict__ midh, const u16* __restrict__ midl,
    const float* __restrict__ wd,
    const int* __restrict__ cnt, const int* __restrict__ list,
    float* __restrict__ downb)
{
  const int p = blockIdx.x;
  const int L = (p & 7) * 64 + (p >> 3);
  const int e = L >> 6;
  const int rem = L & 63;
  const int nu = rem & 31;
  const int tg = rem >> 5;
  const int n0 = nu * 64;
  int ce = cnt[e]; if (ce > MTG * 16) ce = MTG * 16;
  if (ce == 0) return;
  const int ntiers = (ce + 63) >> 6;
  if (tg == 1 && ntiers <= 4) return;

  __shared__ __align__(16) char ldsB[3][8192];

  const int tid = threadIdx.x;
  const int w = tid >> 6, lane = tid & 63;
  const int l15 = lane & 15, lg = lane >> 4;
  const int tier = tg * 4 + w;
  const bool alive = (tier < ntiers);

  // conversion duty: thread -> (oct, nl) column of 8 k
  const int oct = tid >> 6;            // == wave
  const int nl  = tid & 63;
  const int ntgw = nl >> 4;            // 0..3
  const int Lw   = (nl & 15) | (oct << 4);
  const int foh  = ntgw * 1024 + Lw * 16;   // hi frag; lo at +4096
  const float* wsrc = wd + (size_t)e * I * H +
                      (size_t)(oct * 8) * H + (size_t)(n0 + nl);

  const int mt0 = (tier <= 5) ? tier * 4 : MTG - 4;
  const char* pAh = (const char*)midh + (((size_t)e * 32) * MTG + mt0) * 1024 + (size_t)lane * 16;
  const char* pAl = (const char*)midl + (((size_t)e * 32) * MTG + mt0) * 1024 + (size_t)lane * 16;

  f32x4 acc[4][4] = {};
  bf16x8 a0[8], a1[8], a2[8];
  float s0[8], s1[8], s2[8];

#define DN_ISSUE(S, KT) do {                                              \
    const float* ps_ = wsrc + (size_t)(KT) * (32 * (size_t)H);            \
    _Pragma("unroll") for (int j = 0; j < 8; j++) S[j] = ps_[(size_t)j * H]; \
  } while (0)

#define DN_ALOAD(A, KT) do {                                              \
    const size_t ka_ = (size_t)(KT) * (MTG * 1024);                       \
    _Pragma("unroll") for (int q = 0; q < 4; q++) {                       \
      A[q]     = *(const bf16x8*)(pAh + ka_ + q * 1024);                  \
      A[4 + q] = *(const bf16x8*)(pAl + ka_ + q * 1024);                  \
    } } while (0)

#define DN_CONVW(S, WB) do {                                              \
    u16x8 h8_, l8_;                                                       \
    _Pragma("unroll") for (int j = 0; j < 8; j++) {                       \
      const u16 hh_ = bf16rn(S[j]);                                       \
      h8_[j] = hh_; l8_[j] = bf16rn(S[j] - bf16tof(hh_)); }               \
    *(u16x8*)(&ldsB[WB][0] + foh) = h8_;                                  \
    *(u16x8*)(&ldsB[WB][0] + foh + 4096) = l8_;                           \
  } while (0)

#define DN_COMP(RB, A) do {                                               \
    const char* bp_ = &ldsB[RB][0];                                       \
    _Pragma("unroll") for (int ntg = 0; ntg < 4; ntg++) {                 \
      const bf16x8 bh = *(const bf16x8*)(bp_ + ntg * 1024        + lane * 16); \
      const bf16x8 bl = *(const bf16x8*)(bp_ + ntg * 1024 + 4096 + lane * 16); \
      _Pragma("unroll") for (int mi = 0; mi < 4; mi++) {                  \
        acc[mi][ntg] = __builtin_amdgcn_mfma_f32_16x16x32_bf16(A[mi],     bh, acc[mi][ntg], 0, 0, 0); \
        acc[mi][ntg] = __builtin_amdgcn_mfma_f32_16x16x32_bf16(A[mi],     bl, acc[mi][ntg], 0, 0, 0); \
        acc[mi][ntg] = __builtin_amdgcn_mfma_f32_16x16x32_bf16(A[4 + mi], bh, acc[mi][ntg], 0, 0, 0); \
      } } } while (0)

#define DN_BODY(K, SI, AU, AN, SC, RB, WB) do {                           \
    const int k_ = (K);                                                   \
    SYNC();                                                               \
    if (k_ + 3 < 32) DN_ISSUE(SI, k_ + 3);                                \
    if (k_ + 1 < 32) DN_ALOAD(AN, k_ + 1);                                \
    if (alive) DN_COMP(RB, AU);                                           \
    if (k_ + 1 < 32) DN_CONVW(SC, WB);                                    \
  } while (0)

  DN_ISSUE(s0, 0); DN_ISSUE(s1, 1); DN_ISSUE(s2, 2);
  DN_ALOAD(a0, 0);
  DN_CONVW(s0, 0);

  for (int kb = 0; kb < 30; kb += 3) {
    DN_BODY(kb,     s0, a0, a1, s1, 0, 1);
    DN_BODY(kb + 1, s1, a1, a2, s2, 1, 2);
    DN_BODY(kb + 2, s2, a2, a0, s0, 2, 0);
  }
  DN_BODY(30, s0, a0, a1, s1, 0, 1);
  DN_BODY(31, s1, a1, a2, s2, 1, 2);

#undef DN_ISSUE
#undef DN_ALOAD
#undef DN_CONVW
#undef DN_COMP
#undef DN_BODY

#pragma unroll
  for (int mi = 0; mi < 4; mi++) {
#pragma unroll
    for (int rr = 0; rr < 4; rr++) {
      const int m = tier * 64 + mi * 16 + lg * 4 + rr;
      if (m >= ce) continue;
      const int ent  = list[e * T + m];
      const int tok  = ent >> 2;
      const int slot = ent & 3;
      float* drow = downb + ((size_t)tok * TK + slot) * H;
#pragma unroll
      for (int ntg = 0; ntg < 4; ntg++) {
        const int n = n0 + ntg * 16 + l15;
        drow[n] = acc[mi][ntg][rr];
      }
    }
  }
}

// ---------------------------------------------------------------------------
// Combine (unchanged).
// ---------------------------------------------------------------------------
__global__ __launch_bounds__(256) void combine_kernel(
    const float* __restrict__ x, const float* __restrict__ downb,
    const float* __restrict__ wk4, const float* __restrict__ zerow,
    float* __restrict__ out)
{
  const int idx = blockIdx.x * 256 + threadIdx.x;
  const int t   = idx >> 9;
  const int h   = (idx & 511) * 4;

  const float w0 = wk4[t * TK + 0];
  const float w1 = wk4[t * TK + 1];
  const float w2 = wk4[t * TK + 2];
  const float w3 = wk4[t * TK + 3];
  const float zw = zerow[t];

  const float4 xv = *(const float4*)(x + (size_t)t * H + h);
  const float4 d0 = *(const float4*)(downb + ((size_t)t * TK + 0) * H + h);
  const float4 d1 = *(const float4*)(downb + ((size_t)t * TK + 1) * H + h);
  const float4 d2 = *(const float4*)(downb + ((size_t)t * TK + 2) * H + h);
  const float4 d3 = *(const float4*)(downb + ((size_t)t * TK + 3) * H + h);

  float4 o;
  o.x = w0 * d0.x + w1 * d1.x + w2 * d2.x + w3 * d3.x + zw * xv.x;
  o.y = w0 * d0.y + w1 * d1.y + w2 * d2.y + w3 * d3.y + zw * xv.y;
  o.z = w0 * d0.z + w1 * d1.z + w2 * d2.z + w3 * d3.z + zw * xv.z;
  o.w = w0 * d0.w + w1 * d1.w + w2 * d2.w + w3 * d3.w + zw * xv.w;
  *(float4*)(out + (size_t)t * H + h) = o;
}

// ---------------------------------------------------------------------------
// Workspace (~70 MiB): cnt/list/wk4/zerow + Axh/Axl 12.6 MiB ea +
// midh/midl 6.3 MiB ea + downb 32 MiB. No weight-plane round trip.
// ---------------------------------------------------------------------------
extern "C" void kernel_launch(void* const* d_in, const int* in_sizes, int n_in,
                              void* d_out, int out_size, void* d_ws, size_t ws_size,
                              hipStream_t stream) {
  const float* x    = (const float*)d_in[0];
  const float* rw   = (const float*)d_in[1];
  const float* bias = (const float*)d_in[2];
  const float* wg   = (const float*)d_in[3];
  const float* wu   = (const float*)d_in[4];
  const float* wd   = (const float*)d_in[5];
  float* out = (float*)d_out;

  char* ws = (char*)d_ws;
  size_t off = 0;
  auto alloc = [&](size_t bytes) {
    void* p = ws + off;
    off = (off + bytes + 1023) & ~(size_t)1023;
    return p;
  };
  int*   cnt   = (int*)  alloc(E * sizeof(int));
  int*   list  = (int*)  alloc((size_t)E * T * sizeof(int));
  float* wk4   = (float*)alloc((size_t)T * TK * sizeof(float));
  float* zerow = (float*)alloc((size_t)T * sizeof(float));
  const size_t AXSZ = (size_t)E * 64 * MTG * 512;          // elems
  u16*   Axh   = (u16*)  alloc(AXSZ * sizeof(u16));
  u16*   Axl   = (u16*)  alloc(AXSZ * sizeof(u16));
  const size_t MIDSZ = (size_t)E * 32 * MTG * 512;         // elems
  u16*   midh  = (u16*)  alloc(MIDSZ * sizeof(u16));
  u16*   midl  = (u16*)  alloc(MIDSZ * sizeof(u16));
  float* downb = (float*)alloc((size_t)T * TK * H * sizeof(float));
  (void)ws_size;

  hipMemsetAsync(cnt, 0, E * sizeof(int), stream);

  router_kernel<<<T, 256, 0, stream>>>(x, rw, bias, cnt, list, wk4, zerow);
  prep_a_kernel<<<dim3(64, 8), 256, 0, stream>>>(x, cnt, list, Axh, Axl);

  gateup_kernel<<<512, 256, 0, stream>>>(
      Axh, Axl, wg, wu, cnt, list, midh, midl);

  down_kernel<<<512, 256, 0, stream>>>(
      midh, midl, wd, cnt, list, downb);

  combine_kernel<<<(T * H / 4) / 256, 256, 0, stream>>>(
      x, downb, wk4, zerow, out);
}